// Round 10
// baseline (195.322 us; speedup 1.0000x reference)
//
#include <hip/hip_runtime.h>
#include <math.h>

// Problem constants
#define B  16384
#define K  1024
#define D  512
#define EPS 1e-12f

// softmax in base-2: log2(e^{(s+g)/tau}) = SM_C1*s - 10*log2(-log2(u)) + SM_C2
//   tau = 0.1 ; SM_C1 = 10*log2(e) ; SM_C2 = -10*log2(ln 2)
#define SM_C1 14.426950408889634f
#define SM_C2 5.287663729448977f

typedef unsigned short ushort_t;

// raw gfx950 transcendentals: v_log_f32 = log2(x), v_exp_f32 = 2^x
#define LOG2F(x) __builtin_amdgcn_logf(x)
#define EXP2F(x) __builtin_amdgcn_exp2f(x)

// d_out layout (floats): [0, B*D) pt ; [B*D, B*D+K*D) p ; then sim_loss, div_loss
#define OUT_PT   0
#define OUT_P    (B*D)
#define OUT_SIM  (B*D + K*D)
#define OUT_DIV  (B*D + K*D + 1)

// ws layout (floats):
//  [1024,2048)      softmax per-block dot partials (1024)
//  [32768, +B*K/2)  simh f16 [B][1024]; after softmax same bytes hold Eh f16
//  then Ph   [1024][512] f16 (1 MB)
//  then PTh  [512][1024] f16 (1 MB)
//  then DIAGP[256], COLP[256][512]  (norm_p per-block partials, no atomics)
#define WS_RED   1024
#define WS_SIM   32768
#define WS_PH    (WS_SIM + (B*K)/2)
#define WS_PTH   (WS_PH + (K*D)/2)
#define WS_DIAGP (WS_PTH + (K*D)/2)
#define WS_COLP  (WS_DIAGP + 256)

// Xh f16 [16384][512] (16 MB) lives in d_out's pt region, consumed by gemm1
// before gemm2 overwrites pt.

typedef _Float16 half8 __attribute__((ext_vector_type(8)));
typedef float f32x4 __attribute__((ext_vector_type(4)));

__device__ __forceinline__ float wave_reduce_sum(float v) {
    #pragma unroll
    for (int off = 32; off >= 1; off >>= 1) v += __shfl_down(v, off);
    return v;
}
__device__ __forceinline__ double wave_reduce_sum_d(double v) {
    #pragma unroll
    for (int off = 32; off >= 1; off >>= 1) v += __shfl_down(v, off);
    return v;
}
__device__ __forceinline__ float wave_reduce_max(float v) {
    #pragma unroll
    for (int off = 32; off >= 1; off >>= 1) v = fmaxf(v, __shfl_down(v, off));
    return v;
}

__device__ __forceinline__ ushort_t f2h(float f) {
    _Float16 h = (_Float16)f;
    return __builtin_bit_cast(ushort_t, h);
}
__device__ __forceinline__ float h2f(ushort_t u) {
    return (float)__builtin_bit_cast(_Float16, u);
}

__device__ __forceinline__ void async16(const void* g, void* l) {
    __builtin_amdgcn_global_load_lds(
        (const __attribute__((address_space(1))) unsigned int*)g,
        (__attribute__((address_space(3))) unsigned int*)l, 16, 0, 0);
}

// ---------------------------------------------------------------------------
// prep: norm_p (blocks 0..255) || xcvt (blocks 256..4351) — independent work
// merged into one launch to cut graph-launch gaps (round 9: part of -16.7 µs).
// ---------------------------------------------------------------------------
__global__ __launch_bounds__(256) void prep_kernel(const float* __restrict__ proto,
                                                   const float* __restrict__ x,
                                                   float* __restrict__ out,
                                                   float* __restrict__ ws,
                                                   ushort_t* __restrict__ Ph,
                                                   ushort_t* __restrict__ Xh) {
    __shared__ float cs[4][512];
    __shared__ float red[4];
    int tid = threadIdx.x, wid = tid >> 6, lane = tid & 63;

    if (blockIdx.x < 256) {
        // ---- norm_p: normalize prototypes, 4 rows/block ----
        int row = blockIdx.x * 4 + wid;
        const float4* pr = (const float4*)(proto + (size_t)row * D);
        float4 a = pr[lane * 2], b = pr[lane * 2 + 1];
        float ss = a.x*a.x + a.y*a.y + a.z*a.z + a.w*a.w
                 + b.x*b.x + b.y*b.y + b.z*b.z + b.w*b.w;
        ss = wave_reduce_sum(ss);
        ss = __shfl(ss, 0);
        float inv = 1.0f / fmaxf(sqrtf(ss), EPS);
        float4 na = make_float4(a.x*inv, a.y*inv, a.z*inv, a.w*inv);
        float4 nb = make_float4(b.x*inv, b.y*inv, b.z*inv, b.w*inv);
        float4* po = (float4*)(out + OUT_P + (size_t)row * D);
        po[lane * 2]     = na;
        po[lane * 2 + 1] = nb;
        ushort4* ph = (ushort4*)(Ph + (size_t)row * D);
        ph[lane * 2]     = make_ushort4(f2h(na.x), f2h(na.y), f2h(na.z), f2h(na.w));
        ph[lane * 2 + 1] = make_ushort4(f2h(nb.x), f2h(nb.y), f2h(nb.z), f2h(nb.w));
        *(float4*)(&cs[wid][lane * 8])     = na;
        *(float4*)(&cs[wid][lane * 8 + 4]) = nb;
        if (lane == 0) red[wid] = ss * inv * inv;
        __syncthreads();
        float c0 = cs[0][tid] + cs[1][tid] + cs[2][tid] + cs[3][tid];
        float c1 = cs[0][tid + 256] + cs[1][tid + 256] + cs[2][tid + 256] + cs[3][tid + 256];
        ws[WS_COLP + (size_t)blockIdx.x * 512 + tid]       = c0;
        ws[WS_COLP + (size_t)blockIdx.x * 512 + tid + 256] = c1;
        if (tid == 0) ws[WS_DIAGP + blockIdx.x] = red[0] + red[1] + red[2] + red[3];
    } else {
        // ---- xcvt: x row-norm + f16 convert, 4 rows/block ----
        int row = (blockIdx.x - 256) * 4 + wid;
        const float4* xr = (const float4*)(x + (size_t)row * D);
        float4 a = xr[lane * 2], b = xr[lane * 2 + 1];
        float ss = a.x*a.x + a.y*a.y + a.z*a.z + a.w*a.w
                 + b.x*b.x + b.y*b.y + b.z*b.z + b.w*b.w;
        ss = wave_reduce_sum(ss);
        ss = __shfl(ss, 0);
        float inv = 1.0f / fmaxf(sqrtf(ss), EPS);
        ushort4 h0 = make_ushort4(f2h(a.x*inv), f2h(a.y*inv), f2h(a.z*inv), f2h(a.w*inv));
        ushort4 h1 = make_ushort4(f2h(b.x*inv), f2h(b.y*inv), f2h(b.z*inv), f2h(b.w*inv));
        ushort4* xo = (ushort4*)(Xh + (size_t)row * D);
        xo[lane * 2]     = h0;
        xo[lane * 2 + 1] = h1;
    }
}

// ---------------------------------------------------------------------------
// f16 bt-GEMM: m97 128x128 tile/layout + T1 XCD swizzle + piggyback blocks,
// now with T4 counted-vmcnt never-drain pipeline:
//   BK=32 panels double-buffered (LDS 32 KB -> ~5 blocks/CU co-resident);
//   per step: stage(t+1) -> s_waitcnt vmcnt(4) (waits ONLY tile t's 4 loads,
//   t+1's stay in flight across the barrier) -> raw s_barrier -> ds_read +
//   16 MFMA (setprio) -> raw s_barrier. No __syncthreads in-loop (its implicit
//   vmcnt(0) drain is the m97 ~20% stall). Memory layout/addressing identical
//   to the round-9 kernel (risk isolation: only the sync schedule changed).
// Blocks >= NBM*NBN: EXTRA piggyback work (no intra-launch deps):
//   EXTRA==1 (gemm1): ptcvt — PTh transpose of phat (input from prior launch)
//   EXTRA==2 (gemm2): finalize — loss reduction in FP64 (accuracy hedge for
//   the round-9 absmax 0.22 drift; div_loss is a cancellation-heavy form).
// ---------------------------------------------------------------------------
template<int LDA, int LDB, int LDC, int KK, bool F16C, int NBN, int NBM, int EXTRA>
__global__ __launch_bounds__(256) void gemm_bt3(const ushort_t* __restrict__ A,
                                                const ushort_t* __restrict__ Bm,
                                                void* __restrict__ Cv,
                                                const float* __restrict__ phat,
                                                ushort_t* __restrict__ PT,
                                                float* __restrict__ out,
                                                float* __restrict__ ws) {
    __shared__ __align__(16) char smem[32768];   // gemm 32 KB | ptcvt 16.6 KB
    int tid = threadIdx.x;
    int wid = tid >> 6, lane = tid & 63;

    if (blockIdx.x >= NBM * NBN) {
        if (EXTRA == 1) {
            // ---- ptcvt: PTh [512][1024] = transpose of phat, 64x64 tiles ----
            int pid = blockIdx.x - NBM * NBN;          // 0..127
            int k0 = (pid & 15) * 64, d0 = (pid >> 4) * 64;
            float (*tile)[65] = (float(*)[65])smem;
            #pragma unroll
            for (int i = tid; i < 64 * 64; i += 256) {
                int kk = i >> 6, dd = i & 63;
                tile[dd][kk] = phat[(size_t)(k0 + kk) * D + d0 + dd];
            }
            __syncthreads();
            #pragma unroll
            for (int i = tid; i < 64 * 64; i += 256) {
                int dd = i >> 6, kk = i & 63;
                PT[(size_t)(d0 + dd) * K + k0 + kk] = f2h(tile[dd][kk]);
            }
        } else if (EXTRA == 2) {
            // ---- finalize (256 threads, FP64 accumulation) ----
            double* rd = (double*)smem;                // [4]x3 doubles
            double* rs = rd + 4;
            double* rg = rs + 4;
            double vdot = 0.0;
            #pragma unroll
            for (int i = 0; i < 4; ++i) vdot += (double)ws[WS_RED + tid + 256 * i];
            double diag = (double)ws[WS_DIAGP + tid];
            double c0 = 0.0, c1 = 0.0;
            for (int b2 = 0; b2 < 256; ++b2) {
                c0 += (double)ws[WS_COLP + (size_t)b2 * 512 + tid];
                c1 += (double)ws[WS_COLP + (size_t)b2 * 512 + tid + 256];
            }
            double vssq = c0 * c0 + c1 * c1;
            vdot = wave_reduce_sum_d(vdot);
            vssq = wave_reduce_sum_d(vssq);
            diag = wave_reduce_sum_d(diag);
            if (lane == 0) { rd[wid] = vdot; rs[wid] = vssq; rg[wid] = diag; }
            __syncthreads();
            if (tid == 0) {
                double dot = rd[0] + rd[1] + rd[2] + rd[3];
                double ssq = rs[0] + rs[1] + rs[2] + rs[3];
                double dg  = rg[0] + rg[1] + rg[2] + rg[3];
                out[OUT_SIM] = (float)(1.0 - dot * (1.0 / (double)B));
                out[OUT_DIV] = (float)(ssq - dg);
            }
        }
        return;
    }

    // ---- GEMM path ----
    ushort_t* As = (ushort_t*)smem;                    // [2][128*32] halves
    ushort_t* Bs = (ushort_t*)(smem + 16384);          // [2][128*32] halves

    int quad = lane >> 4, l16 = lane & 15;
    int wm = (wid & 1) * 64, wn = (wid >> 1) * 64;

    // XCD-aware block swizzle: xcd = sid&7 owns bm in [xcd*NBM/8, (xcd+1)*NBM/8)
    int sid = blockIdx.x;
    int xcd = sid & 7, slot = sid >> 3;
    int bmb = xcd * (NBM / 8) + slot / NBN;
    int bnb = slot % NBN;
    int bn0 = bnb * 128, bm0 = bmb * 128;

    int ldrow = lane >> 2;           // 0..15
    int lcol  = (lane & 3) * 8;      // 16B chunk within a 32-half panel row

    f32x4 acc[4][4] = {};

    const ushort_t* Ab = A + (size_t)(bm0 + wid * 16 + ldrow) * LDA + lcol;
    const ushort_t* Bb = Bm + (size_t)(bn0 + wid * 16 + ldrow) * LDB + lcol;

    // stage one BK=32 panel (4 loads/thread: A rows 0-63, 64-127; B same)
    auto stage = [&](int buf, int kc) {
        async16(Ab + kc,                    As + buf * 4096 + (wid * 16) * 32);
        async16(Ab + kc + (size_t)64 * LDA, As + buf * 4096 + (64 + wid * 16) * 32);
        async16(Bb + kc,                    Bs + buf * 4096 + (wid * 16) * 32);
        async16(Bb + kc + (size_t)64 * LDB, Bs + buf * 4096 + (64 + wid * 16) * 32);
    };

    constexpr int NT = KK / 32;
    stage(0, 0);
    for (int t = 0; t < NT; ++t) {
        if (t + 1 < NT) {
            stage((t + 1) & 1, (t + 1) * 32);
            asm volatile("s_waitcnt vmcnt(4)" ::: "memory");  // tile t landed
        } else {
            asm volatile("s_waitcnt vmcnt(0)" ::: "memory");  // last tile
        }
        __builtin_amdgcn_s_barrier();
        __builtin_amdgcn_sched_barrier(0);     // no ds_read hoists above barrier
        {
            int buf = t & 1;
            half8 af[4], bg[4];
            #pragma unroll
            for (int i = 0; i < 4; ++i)
                af[i] = *(const half8*)(As + buf * 4096 + (wm + 16 * i + l16) * 32 + quad * 8);
            #pragma unroll
            for (int j = 0; j < 4; ++j)
                bg[j] = *(const half8*)(Bs + buf * 4096 + (wn + 16 * j + l16) * 32 + quad * 8);
            __builtin_amdgcn_s_setprio(1);
            #pragma unroll
            for (int i = 0; i < 4; ++i)
                #pragma unroll
                for (int j = 0; j < 4; ++j)
                    acc[i][j] = __builtin_amdgcn_mfma_f32_16x16x32_f16(af[i], bg[j], acc[i][j], 0, 0, 0);
            __builtin_amdgcn_s_setprio(0);
        }
        if (t + 1 < NT) __builtin_amdgcn_s_barrier();  // all reads of buf done
    }

    #pragma unroll
    for (int i = 0; i < 4; ++i) {
        #pragma unroll
        for (int j = 0; j < 4; ++j) {
            #pragma unroll
            for (int r = 0; r < 4; ++r) {
                int row = bm0 + wm + 16 * i + quad * 4 + r;
                int col = bn0 + wn + 16 * j + l16;
                if (F16C)
                    ((ushort_t*)Cv)[(size_t)row * LDC + col] = f2h(acc[i][j][r]);
                else
                    ((float*)Cv)[(size_t)row * LDC + col] = acc[i][j][r];
            }
        }
    }
}

// Row softmax with gumbel, base-2 domain (2x v_log + 1x v_exp per element).
// One WAVE per row, 4 rows/wave. Reads simh f16, writes Eh f16 in-place.
__global__ __launch_bounds__(256) void softmax_rows(const float* __restrict__ u,
                                                    float* __restrict__ ws) {
    ushort_t* simh = (ushort_t*)(ws + WS_SIM);
    int tid = threadIdx.x;
    int wid = tid >> 6, lane = tid & 63;
    int gw = blockIdx.x * 4 + wid;        // 0..4095
    float dotacc = 0.0f;

    for (int r = 0; r < 4; ++r) {
        int row = gw + 4096 * r;
        ushort4* srow = (ushort4*)(simh + (size_t)row * K);
        const float4* urow = (const float4*)(u + (size_t)row * K);
        float4 s[4], z[4];
        #pragma unroll
        for (int j = 0; j < 4; ++j) {
            ushort4 sh = srow[lane + 64 * j];
            float4 uu = urow[lane + 64 * j];
            s[j] = make_float4(h2f(sh.x), h2f(sh.y), h2f(sh.z), h2f(sh.w));
            z[j].x = SM_C1 * s[j].x - 10.0f * LOG2F(-LOG2F(uu.x)) + SM_C2;
            z[j].y = SM_C1 * s[j].y - 10.0f * LOG2F(-LOG2F(uu.y)) + SM_C2;
            z[j].z = SM_C1 * s[j].z - 10.0f * LOG2F(-LOG2F(uu.z)) + SM_C2;
            z[j].w = SM_C1 * s[j].w - 10.0f * LOG2F(-LOG2F(uu.w)) + SM_C2;
        }
        float m = z[0].x;
        #pragma unroll
        for (int j = 0; j < 4; ++j)
            m = fmaxf(m, fmaxf(fmaxf(z[j].x, z[j].y), fmaxf(z[j].z, z[j].w)));
        m = wave_reduce_max(m);
        m = __shfl(m, 0);

        float4 e[4];
        float l = 0.0f;
        #pragma unroll
        for (int j = 0; j < 4; ++j) {
            e[j].x = EXP2F(z[j].x - m);
            e[j].y = EXP2F(z[j].y - m);
            e[j].z = EXP2F(z[j].z - m);
            e[j].w = EXP2F(z[j].w - m);
            l += e[j].x + e[j].y + e[j].z + e[j].w;
        }
        l = wave_reduce_sum(l);
        l = __shfl(l, 0);
        float inv = 1.0f / l;

        #pragma unroll
        for (int j = 0; j < 4; ++j) {
            float ex = e[j].x * inv, ey = e[j].y * inv,
                  ez = e[j].z * inv, ew = e[j].w * inv;
            srow[lane + 64 * j] = make_ushort4(f2h(ex), f2h(ey), f2h(ez), f2h(ew));
            dotacc += ex * s[j].x + ey * s[j].y + ez * s[j].z + ew * s[j].w;
        }
    }

    dotacc = wave_reduce_sum(dotacc);
    __shared__ float red[4];
    if (lane == 0) red[wid] = dotacc;
    __syncthreads();
    if (tid == 0) ws[WS_RED + blockIdx.x] = red[0] + red[1] + red[2] + red[3];
}

extern "C" void kernel_launch(void* const* d_in, const int* in_sizes, int n_in,
                              void* d_out, int out_size, void* d_ws, size_t ws_size,
                              hipStream_t stream) {
    const float* input  = (const float*)d_in[0];
    const float* proto  = (const float*)d_in[1];
    const float* gumbel = (const float*)d_in[2];
    float* out = (float*)d_out;
    float* ws  = (float*)d_ws;

    ushort_t* Xh   = (ushort_t*)(out + OUT_PT);     // f16 x-hat in pt region
    ushort_t* Ph   = (ushort_t*)(ws + WS_PH);
    ushort_t* PTh  = (ushort_t*)(ws + WS_PTH);
    ushort_t* simh = (ushort_t*)(ws + WS_SIM);      // f16 sim, then Eh in-place

    // 1) norm_p || xcvt (independent)
    prep_kernel<<<256 + B / 4, 256, 0, stream>>>(proto, input, out, ws, Ph, Xh);

    // 2) simh = Xh · Ph^T  (+ piggyback ptcvt blocks: PTh = phat^T)
    gemm_bt3<512, 512, K, 512, true, 8, 128, 1>
        <<<(K / 128) * (B / 128) + 128, 256, 0, stream>>>(
            Xh, Ph, simh, out + OUT_P, PTh, out, ws);

    // 3) row softmax with gumbel (in-place simh -> Eh)
    softmax_rows<<<1024, 256, 0, stream>>>(gumbel, ws);

    // 4) pt = Eh · PTh^T  (+ piggyback finalize block: losses from partials)
    gemm_bt3<1024, 1024, D, 1024, false, 4, 128, 2>
        <<<(D / 128) * (B / 128) + 1, 256, 0, stream>>>(
            simh, PTh, out + OUT_PT, out + OUT_P, PTh, out, ws);
}

// Round 12
// 193.893 us; speedup vs baseline: 1.0074x; 1.0074x over previous
//
#include <hip/hip_runtime.h>
#include <math.h>

// Problem constants
#define B  16384
#define K  1024
#define D  512
#define EPS 1e-12f

// softmax in base-2: log2(e^{(s+g)/tau}) = SM_C1*s - 10*log2(-log2(u)) + SM_C2
//   tau = 0.1 ; SM_C1 = 10*log2(e) ; SM_C2 = -10*log2(ln 2)
#define SM_C1 14.426950408889634f
#define SM_C2 5.287663729448977f

typedef unsigned short ushort_t;

// raw gfx950 transcendentals: v_log_f32 = log2(x), v_exp_f32 = 2^x
#define LOG2F(x) __builtin_amdgcn_logf(x)
#define EXP2F(x) __builtin_amdgcn_exp2f(x)

// d_out layout (floats): [0, B*D) pt ; [B*D, B*D+K*D) p ; then sim_loss, div_loss
#define OUT_PT   0
#define OUT_P    (B*D)
#define OUT_SIM  (B*D + K*D)
#define OUT_DIV  (B*D + K*D + 1)

// ws layout (floats):
//  [1024,2048)      softmax per-block dot partials (1024)
//  [32768, +B*K/2)  simh f16 [B][1024]; after softmax same bytes hold Eh f16
//  then Ph   [1024][512] f16 (1 MB)
//  then PTh  [512][1024] f16 (1 MB)
//  then DIAGP[256], COLP[256][512]  (norm_p per-block partials, no atomics)
#define WS_RED   1024
#define WS_SIM   32768
#define WS_PH    (WS_SIM + (B*K)/2)
#define WS_PTH   (WS_PH + (K*D)/2)
#define WS_DIAGP (WS_PTH + (K*D)/2)
#define WS_COLP  (WS_DIAGP + 256)

// Xh f16 [16384][512] (16 MB) lives in d_out's pt region, consumed by gemm1
// before gemm2 overwrites pt.

typedef _Float16 half8 __attribute__((ext_vector_type(8)));
typedef float f32x4 __attribute__((ext_vector_type(4)));

__device__ __forceinline__ float wave_reduce_sum(float v) {
    #pragma unroll
    for (int off = 32; off >= 1; off >>= 1) v += __shfl_down(v, off);
    return v;
}
__device__ __forceinline__ double wave_reduce_sum_d(double v) {
    #pragma unroll
    for (int off = 32; off >= 1; off >>= 1) v += __shfl_down(v, off);
    return v;
}
__device__ __forceinline__ float wave_reduce_max(float v) {
    #pragma unroll
    for (int off = 32; off >= 1; off >>= 1) v = fmaxf(v, __shfl_down(v, off));
    return v;
}

__device__ __forceinline__ ushort_t f2h(float f) {
    _Float16 h = (_Float16)f;
    return __builtin_bit_cast(ushort_t, h);
}
__device__ __forceinline__ float h2f(ushort_t u) {
    return (float)__builtin_bit_cast(_Float16, u);
}

__device__ __forceinline__ void async16(const void* g, void* l) {
    __builtin_amdgcn_global_load_lds(
        (const __attribute__((address_space(1))) unsigned int*)g,
        (__attribute__((address_space(3))) unsigned int*)l, 16, 0, 0);
}

// ---------------------------------------------------------------------------
// prep: norm_p (blocks 0..255) || xcvt (blocks 256..4351) — independent work
// merged into one launch to cut graph-launch gaps (round 9: part of -16.7 µs).
// ---------------------------------------------------------------------------
__global__ __launch_bounds__(256) void prep_kernel(const float* __restrict__ proto,
                                                   const float* __restrict__ x,
                                                   float* __restrict__ out,
                                                   float* __restrict__ ws,
                                                   ushort_t* __restrict__ Ph,
                                                   ushort_t* __restrict__ Xh) {
    __shared__ float cs[4][512];
    __shared__ float red[4];
    int tid = threadIdx.x, wid = tid >> 6, lane = tid & 63;

    if (blockIdx.x < 256) {
        // ---- norm_p: normalize prototypes, 4 rows/block ----
        int row = blockIdx.x * 4 + wid;
        const float4* pr = (const float4*)(proto + (size_t)row * D);
        float4 a = pr[lane * 2], b = pr[lane * 2 + 1];
        float ss = a.x*a.x + a.y*a.y + a.z*a.z + a.w*a.w
                 + b.x*b.x + b.y*b.y + b.z*b.z + b.w*b.w;
        ss = wave_reduce_sum(ss);
        ss = __shfl(ss, 0);
        float inv = 1.0f / fmaxf(sqrtf(ss), EPS);
        float4 na = make_float4(a.x*inv, a.y*inv, a.z*inv, a.w*inv);
        float4 nb = make_float4(b.x*inv, b.y*inv, b.z*inv, b.w*inv);
        float4* po = (float4*)(out + OUT_P + (size_t)row * D);
        po[lane * 2]     = na;
        po[lane * 2 + 1] = nb;
        ushort4* ph = (ushort4*)(Ph + (size_t)row * D);
        ph[lane * 2]     = make_ushort4(f2h(na.x), f2h(na.y), f2h(na.z), f2h(na.w));
        ph[lane * 2 + 1] = make_ushort4(f2h(nb.x), f2h(nb.y), f2h(nb.z), f2h(nb.w));
        *(float4*)(&cs[wid][lane * 8])     = na;
        *(float4*)(&cs[wid][lane * 8 + 4]) = nb;
        if (lane == 0) red[wid] = ss * inv * inv;
        __syncthreads();
        float c0 = cs[0][tid] + cs[1][tid] + cs[2][tid] + cs[3][tid];
        float c1 = cs[0][tid + 256] + cs[1][tid + 256] + cs[2][tid + 256] + cs[3][tid + 256];
        ws[WS_COLP + (size_t)blockIdx.x * 512 + tid]       = c0;
        ws[WS_COLP + (size_t)blockIdx.x * 512 + tid + 256] = c1;
        if (tid == 0) ws[WS_DIAGP + blockIdx.x] = red[0] + red[1] + red[2] + red[3];
    } else {
        // ---- xcvt: x row-norm + f16 convert, 4 rows/block ----
        int row = (blockIdx.x - 256) * 4 + wid;
        const float4* xr = (const float4*)(x + (size_t)row * D);
        float4 a = xr[lane * 2], b = xr[lane * 2 + 1];
        float ss = a.x*a.x + a.y*a.y + a.z*a.z + a.w*a.w
                 + b.x*b.x + b.y*b.y + b.z*b.z + b.w*b.w;
        ss = wave_reduce_sum(ss);
        ss = __shfl(ss, 0);
        float inv = 1.0f / fmaxf(sqrtf(ss), EPS);
        ushort4 h0 = make_ushort4(f2h(a.x*inv), f2h(a.y*inv), f2h(a.z*inv), f2h(a.w*inv));
        ushort4 h1 = make_ushort4(f2h(b.x*inv), f2h(b.y*inv), f2h(b.z*inv), f2h(b.w*inv));
        ushort4* xo = (ushort4*)(Xh + (size_t)row * D);
        xo[lane * 2]     = h0;
        xo[lane * 2 + 1] = h1;
    }
}

// ---------------------------------------------------------------------------
// f16 bt-GEMM, m97 recipe (BK=64 via two 32-k panels, plain __syncthreads —
// round 10 proved counted-vmcnt variants regress on this structure) +
// T1 XCD swizzle (round 8: -8 µs) + piggyback blocks (round 9: -16.7 µs).
// Blocks >= NBM*NBN: EXTRA work riding the same launch (no intra-launch deps):
//   EXTRA==1 (gemm1): ptcvt — PTh transpose of phat (input from prior launch)
//   EXTRA==2 (gemm2): finalize — loss reduction in FP64 (round 10: fixes the
//   div_loss cancellation drift, absmax 0.22 -> 4.9e-4).
// ---------------------------------------------------------------------------
template<int LDA, int LDB, int LDC, int KK, bool F16C, int NBN, int NBM, int EXTRA>
__global__ __launch_bounds__(256) void gemm_bt2(const ushort_t* __restrict__ A,
                                                const ushort_t* __restrict__ Bm,
                                                void* __restrict__ Cv,
                                                const float* __restrict__ phat,
                                                ushort_t* __restrict__ PT,
                                                float* __restrict__ out,
                                                float* __restrict__ ws) {
    __shared__ __align__(16) char smem[64 * 65 * 4];   // 16.6 KB arena
    int tid = threadIdx.x;
    int wid = tid >> 6, lane = tid & 63;

    if (blockIdx.x >= NBM * NBN) {
        if (EXTRA == 1) {
            // ---- ptcvt: PTh [512][1024] = transpose of phat, 64x64 tiles ----
            int pid = blockIdx.x - NBM * NBN;          // 0..127
            int k0 = (pid & 15) * 64, d0 = (pid >> 4) * 64;
            float (*tile)[65] = (float(*)[65])smem;
            #pragma unroll
            for (int i = tid; i < 64 * 64; i += 256) {
                int kk = i >> 6, dd = i & 63;
                tile[dd][kk] = phat[(size_t)(k0 + kk) * D + d0 + dd];
            }
            __syncthreads();
            #pragma unroll
            for (int i = tid; i < 64 * 64; i += 256) {
                int dd = i >> 6, kk = i & 63;
                PT[(size_t)(d0 + dd) * K + k0 + kk] = f2h(tile[dd][kk]);
            }
        } else if (EXTRA == 2) {
            // ---- finalize (256 threads, FP64 accumulation) ----
            double* rd = (double*)smem;                // [4]x3 doubles
            double* rs = rd + 4;
            double* rg = rs + 4;
            double vdot = 0.0;
            #pragma unroll
            for (int i = 0; i < 4; ++i) vdot += (double)ws[WS_RED + tid + 256 * i];
            double diag = (double)ws[WS_DIAGP + tid];
            double c0 = 0.0, c1 = 0.0;
            for (int b2 = 0; b2 < 256; ++b2) {
                c0 += (double)ws[WS_COLP + (size_t)b2 * 512 + tid];
                c1 += (double)ws[WS_COLP + (size_t)b2 * 512 + tid + 256];
            }
            double vssq = c0 * c0 + c1 * c1;
            vdot = wave_reduce_sum_d(vdot);
            vssq = wave_reduce_sum_d(vssq);
            diag = wave_reduce_sum_d(diag);
            if (lane == 0) { rd[wid] = vdot; rs[wid] = vssq; rg[wid] = diag; }
            __syncthreads();
            if (tid == 0) {
                double dot = rd[0] + rd[1] + rd[2] + rd[3];
                double ssq = rs[0] + rs[1] + rs[2] + rs[3];
                double dg  = rg[0] + rg[1] + rg[2] + rg[3];
                out[OUT_SIM] = (float)(1.0 - dot * (1.0 / (double)B));
                out[OUT_DIV] = (float)(ssq - dg);
            }
        }
        return;
    }

    // ---- GEMM path (m97 recipe, unchanged from round 9) ----
    ushort_t* As = (ushort_t*)smem;                    // 2*128*32 halves = 8 KB
    ushort_t* Bs = (ushort_t*)(smem + 8192);

    int quad = lane >> 4, l16 = lane & 15;
    int wm = (wid & 1) * 64, wn = (wid >> 1) * 64;

    // XCD-aware block swizzle: xcd = sid&7 owns bm in [xcd*NBM/8, (xcd+1)*NBM/8)
    int sid = blockIdx.x;
    int xcd = sid & 7, slot = sid >> 3;
    int bmb = xcd * (NBM / 8) + slot / NBN;
    int bnb = slot % NBN;
    int bn0 = bnb * 128, bm0 = bmb * 128;

    int ldrow = lane >> 2;           // 0..15
    int lcol  = (lane & 3) * 8;      // halves within a 32-half panel row

    f32x4 acc[4][4] = {};

    // wave-uniform LDS staging bases: panel p, row-group q
    ushort_t* AsD[2][2] = {
        { As + (wid * 16) * 32,        As + (64 + wid * 16) * 32 },
        { As + 4096 + (wid * 16) * 32, As + 4096 + (64 + wid * 16) * 32 } };
    ushort_t* BsD[2][2] = {
        { Bs + (wid * 16) * 32,        Bs + (64 + wid * 16) * 32 },
        { Bs + 4096 + (wid * 16) * 32, Bs + 4096 + (64 + wid * 16) * 32 } };

    const ushort_t* Ab = A + (size_t)(bm0 + wid * 16 + ldrow) * LDA + lcol;
    const ushort_t* Bb = Bm + (size_t)(bn0 + wid * 16 + ldrow) * LDB + lcol;

    for (int kc = 0; kc < KK; kc += 64) {
        async16(Ab + kc,                       AsD[0][0]);
        async16(Ab + kc + (size_t)64 * LDA,    AsD[0][1]);
        async16(Ab + kc + 32,                  AsD[1][0]);
        async16(Ab + kc + 32 + (size_t)64*LDA, AsD[1][1]);
        async16(Bb + kc,                       BsD[0][0]);
        async16(Bb + kc + (size_t)64 * LDB,    BsD[0][1]);
        async16(Bb + kc + 32,                  BsD[1][0]);
        async16(Bb + kc + 32 + (size_t)64*LDB, BsD[1][1]);
        __syncthreads();
        #pragma unroll
        for (int p = 0; p < 2; ++p) {
            half8 af[4], bg[4];
            #pragma unroll
            for (int i = 0; i < 4; ++i)
                af[i] = *(const half8*)(As + p * 4096 + (wm + 16 * i + l16) * 32 + quad * 8);
            #pragma unroll
            for (int j = 0; j < 4; ++j)
                bg[j] = *(const half8*)(Bs + p * 4096 + (wn + 16 * j + l16) * 32 + quad * 8);
            #pragma unroll
            for (int i = 0; i < 4; ++i)
                #pragma unroll
                for (int j = 0; j < 4; ++j)
                    acc[i][j] = __builtin_amdgcn_mfma_f32_16x16x32_f16(af[i], bg[j], acc[i][j], 0, 0, 0);
        }
        __syncthreads();
    }
    #pragma unroll
    for (int i = 0; i < 4; ++i) {
        #pragma unroll
        for (int j = 0; j < 4; ++j) {
            #pragma unroll
            for (int r = 0; r < 4; ++r) {
                int row = bm0 + wm + 16 * i + quad * 4 + r;
                int col = bn0 + wn + 16 * j + l16;
                if (F16C)
                    ((ushort_t*)Cv)[(size_t)row * LDC + col] = f2h(acc[i][j][r]);
                else
                    ((float*)Cv)[(size_t)row * LDC + col] = acc[i][j][r];
            }
        }
    }
}

// Row softmax with gumbel, base-2 domain (2x v_log + 1x v_exp per element).
// One WAVE per row, 4 rows/wave. Reads simh f16, writes Eh f16 in-place.
__global__ __launch_bounds__(256) void softmax_rows(const float* __restrict__ u,
                                                    float* __restrict__ ws) {
    ushort_t* simh = (ushort_t*)(ws + WS_SIM);
    int tid = threadIdx.x;
    int wid = tid >> 6, lane = tid & 63;
    int gw = blockIdx.x * 4 + wid;        // 0..4095
    float dotacc = 0.0f;

    for (int r = 0; r < 4; ++r) {
        int row = gw + 4096 * r;
        ushort4* srow = (ushort4*)(simh + (size_t)row * K);
        const float4* urow = (const float4*)(u + (size_t)row * K);
        float4 s[4], z[4];
        #pragma unroll
        for (int j = 0; j < 4; ++j) {
            ushort4 sh = srow[lane + 64 * j];
            float4 uu = urow[lane + 64 * j];
            s[j] = make_float4(h2f(sh.x), h2f(sh.y), h2f(sh.z), h2f(sh.w));
            z[j].x = SM_C1 * s[j].x - 10.0f * LOG2F(-LOG2F(uu.x)) + SM_C2;
            z[j].y = SM_C1 * s[j].y - 10.0f * LOG2F(-LOG2F(uu.y)) + SM_C2;
            z[j].z = SM_C1 * s[j].z - 10.0f * LOG2F(-LOG2F(uu.z)) + SM_C2;
            z[j].w = SM_C1 * s[j].w - 10.0f * LOG2F(-LOG2F(uu.w)) + SM_C2;
        }
        float m = z[0].x;
        #pragma unroll
        for (int j = 0; j < 4; ++j)
            m = fmaxf(m, fmaxf(fmaxf(z[j].x, z[j].y), fmaxf(z[j].z, z[j].w)));
        m = wave_reduce_max(m);
        m = __shfl(m, 0);

        float4 e[4];
        float l = 0.0f;
        #pragma unroll
        for (int j = 0; j < 4; ++j) {
            e[j].x = EXP2F(z[j].x - m);
            e[j].y = EXP2F(z[j].y - m);
            e[j].z = EXP2F(z[j].z - m);
            e[j].w = EXP2F(z[j].w - m);
            l += e[j].x + e[j].y + e[j].z + e[j].w;
        }
        l = wave_reduce_sum(l);
        l = __shfl(l, 0);
        float inv = 1.0f / l;

        #pragma unroll
        for (int j = 0; j < 4; ++j) {
            float ex = e[j].x * inv, ey = e[j].y * inv,
                  ez = e[j].z * inv, ew = e[j].w * inv;
            srow[lane + 64 * j] = make_ushort4(f2h(ex), f2h(ey), f2h(ez), f2h(ew));
            dotacc += ex * s[j].x + ey * s[j].y + ez * s[j].z + ew * s[j].w;
        }
    }

    dotacc = wave_reduce_sum(dotacc);
    __shared__ float red[4];
    if (lane == 0) red[wid] = dotacc;
    __syncthreads();
    if (tid == 0) ws[WS_RED + blockIdx.x] = red[0] + red[1] + red[2] + red[3];
}

extern "C" void kernel_launch(void* const* d_in, const int* in_sizes, int n_in,
                              void* d_out, int out_size, void* d_ws, size_t ws_size,
                              hipStream_t stream) {
    const float* input  = (const float*)d_in[0];
    const float* proto  = (const float*)d_in[1];
    const float* gumbel = (const float*)d_in[2];
    float* out = (float*)d_out;
    float* ws  = (float*)d_ws;

    ushort_t* Xh   = (ushort_t*)(out + OUT_PT);     // f16 x-hat in pt region
    ushort_t* Ph   = (ushort_t*)(ws + WS_PH);
    ushort_t* PTh  = (ushort_t*)(ws + WS_PTH);
    ushort_t* simh = (ushort_t*)(ws + WS_SIM);      // f16 sim, then Eh in-place

    // 1) norm_p || xcvt (independent)
    prep_kernel<<<256 + B / 4, 256, 0, stream>>>(proto, input, out, ws, Ph, Xh);

    // 2) simh = Xh · Ph^T  (+ piggyback ptcvt blocks: PTh = phat^T)
    gemm_bt2<512, 512, K, 512, true, 8, 128, 1>
        <<<(K / 128) * (B / 128) + 128, 256, 0, stream>>>(
            Xh, Ph, simh, out + OUT_P, PTh, out, ws);

    // 3) row softmax with gumbel (in-place simh -> Eh)
    softmax_rows<<<1024, 256, 0, stream>>>(gumbel, ws);

    // 4) pt = Eh · PTh^T  (+ piggyback finalize block: losses from partials)
    gemm_bt2<1024, 1024, D, 1024, false, 4, 128, 2>
        <<<(D / 128) * (B / 128) + 1, 256, 0, stream>>>(
            simh, PTh, out + OUT_PT, out + OUT_P, PTh, out, ws);
}